// Round 1
// baseline (96.990 us; speedup 1.0000x reference)
//
#include <hip/hip_runtime.h>

#define NMAX   64
#define NSITES 12
#define SPLIT  2      // threads per batch element (each handles 6 sites)
#define BLOCK  256

// LDS row stride of 65 float2 (130 dwords, 130 % 32 == 2) so the two lanes of
// an element pair (sites s and s+6 -> rows differ by 6*130 = 780 ≡ 12 mod 32)
// read different banks: conflict-free ds_read_b64 broadcast.
__global__ __launch_bounds__(BLOCK, 4)
void pot_energy_kernel(const float* __restrict__ x,
                       const float* __restrict__ neighbors,
                       float* __restrict__ out, int B) {
    __shared__ float2 nb[NSITES * 65];

    const int tid = threadIdx.x;
    // Cooperative stage of neighbor positions: 768 float2 = 6 KB.
    for (int idx = tid; idx < NSITES * NMAX; idx += BLOCK) {
        const int i = idx >> 6;   // site
        const int j = idx & 63;   // neighbor
        nb[i * 65 + j] = ((const float2*)neighbors)[idx];
    }
    __syncthreads();

    const int gtid = blockIdx.x * BLOCK + tid;
    const int e = gtid >> 1;      // batch element
    const int h = gtid & 1;       // which half of the 12 sites
    if (e >= B) return;

    // This thread's 6 site positions: x[e*24 + h*12 .. +12) == x + gtid*12.
    // 48 B per thread, 16 B aligned, consecutive threads contiguous.
    const float4* xp = (const float4*)(x + (size_t)gtid * 12);
    const float4 a0 = xp[0], a1 = xp[1], a2 = xp[2];
    const float xs_[6] = { a0.x, a0.z, a1.x, a1.z, a2.x, a2.z };
    const float ys_[6] = { a0.y, a0.w, a1.y, a1.w, a2.y, a2.w };

    float acc0 = 0.f, acc1 = 0.f;
    #pragma unroll
    for (int s = 0; s < 6; ++s) {
        const float xs = xs_[s];
        const float ys = ys_[s];
        const float2* __restrict__ row = &nb[(h * 6 + s) * 65];
        #pragma unroll 8
        for (int j = 0; j < NMAX; ++j) {
            const float2 n = row[j];
            const float dx = xs - n.x;
            const float dy = ys - n.y;
            const float r2 = fmaf(dy, dy, dx * dx);
            const float r  = __builtin_amdgcn_sqrtf(r2);
            // Padded neighbors (FAR=1e6) give r~1.4e6 -> exp underflows to
            // exactly 0, so no mask needed.
            const float ex = __expf(-r);
            const float rc = __builtin_amdgcn_rcpf(r + 0.01f);
            if (j & 1) acc1 = fmaf(ex, rc, acc1);
            else       acc0 = fmaf(ex, rc, acc0);
        }
    }

    float total = acc0 + acc1;
    total += __shfl_xor(total, 1);   // combine the two halves of the element
    if (h == 0) out[e] = total;
}

extern "C" void kernel_launch(void* const* d_in, const int* in_sizes, int n_in,
                              void* d_out, int out_size, void* d_ws, size_t ws_size,
                              hipStream_t stream) {
    const float* x   = (const float*)d_in[0];
    const float* nbr = (const float*)d_in[1];
    // d_in[2] = mask: unused — FAR padding makes masked terms exactly 0.
    float* out = (float*)d_out;

    const int B = in_sizes[0] / 24;
    const int total_threads = B * SPLIT;
    const int blocks = (total_threads + BLOCK - 1) / BLOCK;
    pot_energy_kernel<<<blocks, BLOCK, 0, stream>>>(x, nbr, out, B);
}

// Round 3
// 86.760 us; speedup vs baseline: 1.1179x; 1.1179x over previous
//
#include <hip/hip_runtime.h>

#define NMAX   64
#define NSITES 12
#define SPLIT  4      // threads per batch element (each handles 3 sites)
#define BLOCK  256
#define ROWS   66     // LDS row stride in float2: 132 dwords == 4 mod 32 ->
                      // the 4 rows {s, s+3, s+6, s+9} read per wave-op hit
                      // distinct banks (offsets 0,12,24,4 mod 32)

#define LOG2E  1.44269504088896340736f
#define LN2    0.69314718055994530942f
#define B_SOFT 0.01f
#define PAD_C  2.0e6f  // sentinel (already log2e-scaled): exp2(-~3e6) == 0

__global__ __launch_bounds__(BLOCK, 8)
void pot_energy_kernel(const float* __restrict__ x,
                       const float* __restrict__ neighbors,
                       const float* __restrict__ mask,
                       float* __restrict__ out, int B) {
    __shared__ float2 nb[NSITES * ROWS];  // coords pre-scaled by log2(e)
    __shared__ int    cnt[NSITES];

    const int tid  = threadIdx.x;
    const int wv   = tid >> 6;   // wave id 0..3
    const int lane = tid & 63;

    // Fill with sentinel so iterations past a site's compacted count
    // contribute exactly 0 (exp2 underflow), enabling one uniform bound.
    for (int idx = tid; idx < NSITES * ROWS; idx += BLOCK)
        nb[idx] = make_float2(PAD_C, PAD_C);
    __syncthreads();

    // Ballot-compaction of neighbor lists: drop masked (padded) entries.
    // Wave wv handles sites wv, wv+4, wv+8; lane j inspects neighbor j.
    for (int s = wv; s < NSITES; s += 4) {
        const bool keep = mask[s * NMAX + lane] > 0.5f;
        const unsigned long long bal = __ballot(keep);
        if (keep) {
            const int pos = __popcll(bal & ((1ull << lane) - 1ull));
            const float2 p = ((const float2*)neighbors)[s * NMAX + lane];
            nb[s * ROWS + pos] = make_float2(p.x * LOG2E, p.y * LOG2E);
        }
        if (lane == 0) cnt[s] = __popcll(bal);
    }
    __syncthreads();

    // Uniform loop bound: max count over ALL sites — identical in every
    // lane (fixes R2's bug where cnt[site] varied per lane but was
    // broadcast from lane 0). Extra iterations hit the sentinel -> +0.
    int m = 0;
    #pragma unroll
    for (int s = 0; s < NSITES; ++s) m = max(m, cnt[s]);  // LDS broadcast
    m = __builtin_amdgcn_readfirstlane(m);

    const int gtid = blockIdx.x * BLOCK + tid;
    const int e = gtid >> 2;      // batch element
    const int q = gtid & 3;       // which 3-site group
    if (e >= B) return;

    // This thread's 3 site positions: 6 consecutive floats, 8B-aligned,
    // consecutive lanes contiguous -> coalesced dwordx2 loads.
    const float2* xp = (const float2*)(x + (size_t)gtid * 6);
    const float2 p0 = xp[0], p1 = xp[1], p2 = xp[2];
    const float xs_[3] = { p0.x * LOG2E, p1.x * LOG2E, p2.x * LOG2E };
    const float ys_[3] = { p0.y * LOG2E, p1.y * LOG2E, p2.y * LOG2E };

    float acc = 0.f;
    #pragma unroll
    for (int s = 0; s < 3; ++s) {
        const int site = q * 3 + s;
        const float xs = xs_[s];
        const float ys = ys_[s];
        const float2* __restrict__ row = &nb[site * ROWS];
        #pragma unroll 8
        for (int j = 0; j < m; ++j) {
            const float2 nj = row[j];
            const float dx = xs - nj.x;              // = log2e * (x - nx)
            const float dy = ys - nj.y;
            const float r2 = fmaf(dy, dy, dx * dx);  // = (log2e * r)^2
            const float rp = __builtin_amdgcn_sqrtf(r2);       // log2e * r
            const float ex = __builtin_amdgcn_exp2f(-rp);      // exp(-r)
            const float dn = fmaf(rp, LN2, B_SOFT);            // r + b
            acc = fmaf(ex, __builtin_amdgcn_rcpf(dn), acc);
        }
    }

    // Combine the 4 partial sums of element e (lanes q=0..3).
    acc += __shfl_xor(acc, 1);
    acc += __shfl_xor(acc, 2);
    if (q == 0) out[e] = acc;
}

extern "C" void kernel_launch(void* const* d_in, const int* in_sizes, int n_in,
                              void* d_out, int out_size, void* d_ws, size_t ws_size,
                              hipStream_t stream) {
    const float* x   = (const float*)d_in[0];
    const float* nbr = (const float*)d_in[1];
    const float* msk = (const float*)d_in[2];
    float* out = (float*)d_out;

    const int B = in_sizes[0] / 24;
    const int total_threads = B * SPLIT;
    const int blocks = (total_threads + BLOCK - 1) / BLOCK;
    pot_energy_kernel<<<blocks, BLOCK, 0, stream>>>(x, nbr, msk, out, B);
}

// Round 4
// 86.507 us; speedup vs baseline: 1.1212x; 1.0029x over previous
//
#include <hip/hip_runtime.h>

#define NMAX   64
#define NSITES 12
#define SPLIT  4      // threads per batch element (each handles 3 sites)
#define BLOCK  256
#define ROWS   66     // LDS row stride in float2: 132 dwords == 4 mod 32; also
                      // 66*8 B = 16B-aligned rows so float4 reads are legal

#define LOG2E  1.44269504088896340736f
#define LN2    0.69314718055994530942f
#define B_SOFT 0.01f
#define PAD_C  2.0e6f  // sentinel (log2e-scaled): exp2(-~2.8e6)==0, d~2e6
                       // -> d^4 ~ 1.5e25 stays in f32 range for rcp-batching

__global__ __launch_bounds__(BLOCK, 8)
void pot_energy_kernel(const float* __restrict__ x,
                       const float* __restrict__ neighbors,
                       const float* __restrict__ mask,
                       float* __restrict__ out, int B) {
    __shared__ float2 nb[NSITES * ROWS];  // coords pre-scaled by log2(e)
    __shared__ int    cnt[NSITES];

    const int tid  = threadIdx.x;
    const int wv   = tid >> 6;
    const int lane = tid & 63;

    // Sentinel fill: iterations past a site's compacted count contribute
    // exactly 0 (exp2 underflow), enabling one uniform loop bound.
    for (int idx = tid; idx < NSITES * ROWS; idx += BLOCK)
        nb[idx] = make_float2(PAD_C, PAD_C);
    __syncthreads();

    // Ballot-compaction of neighbor lists (drop masked padding, ~64->~58).
    for (int s = wv; s < NSITES; s += 4) {
        const bool keep = mask[s * NMAX + lane] > 0.5f;
        const unsigned long long bal = __ballot(keep);
        if (keep) {
            const int pos = __popcll(bal & ((1ull << lane) - 1ull));
            const float2 p = ((const float2*)neighbors)[s * NMAX + lane];
            nb[s * ROWS + pos] = make_float2(p.x * LOG2E, p.y * LOG2E);
        }
        if (lane == 0) cnt[s] = __popcll(bal);
    }
    __syncthreads();

    // Uniform bound: max count over ALL sites (identical in every lane),
    // rounded up to a multiple of 4 for the rcp-batched chunks.
    int m = 0;
    #pragma unroll
    for (int s = 0; s < NSITES; ++s) m = max(m, cnt[s]);
    m = (__builtin_amdgcn_readfirstlane(m) + 3) & ~3;   // <= 64 <= ROWS

    const int gtid = blockIdx.x * BLOCK + tid;
    const int e = gtid >> 2;      // batch element
    const int q = gtid & 3;       // which 3-site group
    if (e >= B) return;

    const float2* xp = (const float2*)(x + (size_t)gtid * 6);
    const float2 p0 = xp[0], p1 = xp[1], p2 = xp[2];
    const float xs_[3] = { p0.x * LOG2E, p1.x * LOG2E, p2.x * LOG2E };
    const float ys_[3] = { p0.y * LOG2E, p1.y * LOG2E, p2.y * LOG2E };

    float acc0 = 0.f, acc1 = 0.f;
    #pragma unroll
    for (int s = 0; s < 3; ++s) {
        const int site = q * 3 + s;
        const float xs = xs_[s];
        const float ys = ys_[s];
        const float4* __restrict__ row4 = (const float4*)&nb[site * ROWS];
        #pragma unroll 2
        for (int j0 = 0; j0 < m; j0 += 4) {
            const float4 ab = row4[(j0 >> 1) + 0];  // neighbors j0, j0+1
            const float4 cd = row4[(j0 >> 1) + 1];  // neighbors j0+2, j0+3
            const float nx[4] = { ab.x, ab.z, cd.x, cd.z };
            const float ny[4] = { ab.y, ab.w, cd.y, cd.w };
            float exv[4], dv[4];
            #pragma unroll
            for (int k = 0; k < 4; ++k) {
                const float dx = xs - nx[k];             // log2e * (x - nx)
                const float dy = ys - ny[k];
                const float r2 = fmaf(dy, dy, dx * dx);  // (log2e * r)^2
                const float rp = __builtin_amdgcn_sqrtf(r2);   // log2e * r
                exv[k] = __builtin_amdgcn_exp2f(-rp);          // exp(-r)
                dv[k]  = fmaf(rp, LN2, B_SOFT);                // r + b
            }
            // One rcp for four denominators: R = 1/(d0 d1 d2 d3).
            const float p01 = dv[0] * dv[1];
            const float p23 = dv[2] * dv[3];
            const float R   = __builtin_amdgcn_rcpf(p01 * p23);
            const float t01 = p23 * R;   // 1/(d0*d1)
            const float t23 = p01 * R;   // 1/(d2*d3)
            acc0 = fmaf(exv[0] * dv[1], t01, acc0);   // ex0/d0
            acc1 = fmaf(exv[1] * dv[0], t01, acc1);   // ex1/d1
            acc0 = fmaf(exv[2] * dv[3], t23, acc0);   // ex2/d2
            acc1 = fmaf(exv[3] * dv[2], t23, acc1);   // ex3/d3
        }
    }

    float acc = acc0 + acc1;
    acc += __shfl_xor(acc, 1);   // combine the 4 partial sums of element e
    acc += __shfl_xor(acc, 2);
    if (q == 0) out[e] = acc;
}

extern "C" void kernel_launch(void* const* d_in, const int* in_sizes, int n_in,
                              void* d_out, int out_size, void* d_ws, size_t ws_size,
                              hipStream_t stream) {
    const float* x   = (const float*)d_in[0];
    const float* nbr = (const float*)d_in[1];
    const float* msk = (const float*)d_in[2];
    float* out = (float*)d_out;

    const int B = in_sizes[0] / 24;
    const int total_threads = B * SPLIT;
    const int blocks = (total_threads + BLOCK - 1) / BLOCK;
    pot_energy_kernel<<<blocks, BLOCK, 0, stream>>>(x, nbr, msk, out, B);
}